// Round 1
// baseline (401.553 us; speedup 1.0000x reference)
//
#include <hip/hip_runtime.h>

#define L2E 1.4426950408889634f
#define LN2 0.6931471805599453f

__device__ __forceinline__ float dexp2(float x) { return __builtin_amdgcn_exp2f(x); }
__device__ __forceinline__ float dlog2(float x) { return __builtin_amdgcn_logf(x); }

// CRF forward (log-partition) + gold score, fused. One batch per 32 lanes,
// 2 batches per wave, 1 wave per block. grid=256 -> 1 block/CU.
__global__ __launch_bounds__(64) void crf_nll_kernel(
    const float* __restrict__ em,   // [512][2048][32] emissions
    const float* __restrict__ tr,   // [32][32] transitions[tag][prev]
    const int*   __restrict__ tgs,  // [512][2048] gold tags
    float*       __restrict__ ws)   // [512] per-batch (logZ - gold)
{
    __shared__ float s_tr[32 * 32];
    __shared__ float s_ex[2][32];

    const int tid = threadIdx.x;
    const int h   = tid >> 5;    // which batch within the wave
    const int tag = tid & 31;    // lane = tag
    const int b   = (int)blockIdx.x * 2 + h;

    for (int k = tid; k < 1024; k += 64) s_tr[k] = tr[k];
    __syncthreads();

    // E[p] = exp(trans[tag][p]) computed as 2^(trans * log2e). Exact zeros for
    // the -10000 entries (START row, STOP column) -> matches reference lse.
    float E[32];
#pragma unroll
    for (int p = 0; p < 32; ++p) E[p] = dexp2(s_tr[tag * 32 + p] * L2E);

    const float* eb = em + (size_t)b * (2048 * 32) + tag;
    const int*   tb = tgs + (size_t)b * 2048;

    float eA[8], eB[8];   // raw emissions, double-buffered 8-step chunks
    int   tA[8], tB[8];   // gold tags for the chunk

#define LOADCH(EBUF, TBUF, C) do { \
    const int _t0 = (C) * 8; \
    _Pragma("unroll") for (int _i = 0; _i < 8; ++_i) EBUF[_i] = eb[(_t0 + _i) * 32]; \
    _Pragma("unroll") for (int _i = 0; _i < 8; ++_i) TBUF[_i] = tb[_t0 + _i]; \
} while (0)

    float A = 0.f;     // alpha[tag] in log2 units, relative to 'base'
    float base = 0.f;  // accumulated rescale offset (log2 units)
    float gt = 0.f;    // gold transition score (natural log units, wave-uniform)
    float ge = 0.f;    // gold emission score (this lane's contributions, natural)
    int tprev = 0;

#define RESCALE do { \
    float _m = A; \
    _m = fmaxf(_m, __shfl_xor(_m, 1, 32)); \
    _m = fmaxf(_m, __shfl_xor(_m, 2, 32)); \
    _m = fmaxf(_m, __shfl_xor(_m, 4, 32)); \
    _m = fmaxf(_m, __shfl_xor(_m, 8, 32)); \
    _m = fmaxf(_m, __shfl_xor(_m, 16, 32)); \
    base += _m; A -= _m; \
} while (0)

    // One forward step at time t (t>=1): exp-domain matvec against E.
#define STEP(EV, TT) do { \
    float _ex = dexp2(A); \
    s_ex[h][tag] = _ex; \
    float _a0 = 0.f, _a1 = 0.f, _a2 = 0.f, _a3 = 0.f; \
    _Pragma("unroll") for (int _j = 0; _j < 8; ++_j) { \
        float4 _x = *(const float4*)(&s_ex[h][_j * 4]); \
        _a0 = fmaf(E[_j * 4 + 0], _x.x, _a0); \
        _a1 = fmaf(E[_j * 4 + 1], _x.y, _a1); \
        _a2 = fmaf(E[_j * 4 + 2], _x.z, _a2); \
        _a3 = fmaf(E[_j * 4 + 3], _x.w, _a3); \
    } \
    float _acc = (_a0 + _a1) + (_a2 + _a3); \
    A = fmaf((EV), L2E, dlog2(_acc)); \
    const int _tt = (TT); \
    gt += s_tr[_tt * 32 + tprev]; \
    ge += (tag == _tt) ? (EV) : 0.f; \
    tprev = _tt; \
} while (0)

    // ---- chunk 0 (t = 0..7): t=0 is the init step ----
    LOADCH(eA, tA, 0);
    LOADCH(eB, tB, 1);
    {
        float ev = eA[0];
        int   tt = tA[0];
        A  = (s_tr[tag * 32 + 30] + ev) * L2E;   // trans[tag][START] + e0
        gt = s_tr[tt * 32 + 30];                  // trans[tags0][START]
        ge = (tag == tt) ? ev : 0.f;
        tprev = tt;
    }
#pragma unroll
    for (int i = 1; i < 8; ++i) STEP(eA[i], tA[i]);

    // ---- chunks 1..254, two per iteration (static buffer roles) ----
    for (int c = 1; c < 255; c += 2) {
        LOADCH(eA, tA, c + 1);
        RESCALE;
#pragma unroll
        for (int i = 0; i < 8; ++i) STEP(eB[i], tB[i]);
        LOADCH(eB, tB, c + 2);
        RESCALE;
#pragma unroll
        for (int i = 0; i < 8; ++i) STEP(eA[i], tA[i]);
    }
    // ---- final chunk 255 ----
    RESCALE;
#pragma unroll
    for (int i = 0; i < 8; ++i) STEP(eB[i], tB[i]);

    // ---- epilogue: logZ and gold finish ----
    float v = fmaf(s_tr[31 * 32 + tag], L2E, A);   // + trans[STOP][tag]
    float m = v;
    m = fmaxf(m, __shfl_xor(m, 1, 32));
    m = fmaxf(m, __shfl_xor(m, 2, 32));
    m = fmaxf(m, __shfl_xor(m, 4, 32));
    m = fmaxf(m, __shfl_xor(m, 8, 32));
    m = fmaxf(m, __shfl_xor(m, 16, 32));
    float sx = dexp2(v - m);
    sx += __shfl_xor(sx, 1, 32);
    sx += __shfl_xor(sx, 2, 32);
    sx += __shfl_xor(sx, 4, 32);
    sx += __shfl_xor(sx, 8, 32);
    sx += __shfl_xor(sx, 16, 32);
    float logZ = (base + m + dlog2(sx)) * LN2;     // back to natural log

    float g = ge;
    g += __shfl_xor(g, 1, 32);
    g += __shfl_xor(g, 2, 32);
    g += __shfl_xor(g, 4, 32);
    g += __shfl_xor(g, 8, 32);
    g += __shfl_xor(g, 16, 32);
    gt += s_tr[31 * 32 + tprev];                   // trans[STOP][tags_last]

    if (tag == 0) ws[b] = logZ - g - gt;
#undef STEP
#undef RESCALE
#undef LOADCH
}

// Deterministic fixed-order reduction of the 512 per-batch values.
__global__ __launch_bounds__(64) void crf_reduce_kernel(
    const float* __restrict__ ws, float* __restrict__ out)
{
    int l = threadIdx.x;
    float s = 0.f;
#pragma unroll
    for (int k = 0; k < 8; ++k) s += ws[l + k * 64];
    s += __shfl_xor(s, 1, 64);
    s += __shfl_xor(s, 2, 64);
    s += __shfl_xor(s, 4, 64);
    s += __shfl_xor(s, 8, 64);
    s += __shfl_xor(s, 16, 64);
    s += __shfl_xor(s, 32, 64);
    if (l == 0) out[0] = s;
}

extern "C" void kernel_launch(void* const* d_in, const int* in_sizes, int n_in,
                              void* d_out, int out_size, void* d_ws, size_t ws_size,
                              hipStream_t stream)
{
    const float* em = (const float*)d_in[0];   // emissions f32 [512*2048*32]
    const float* tr = (const float*)d_in[1];   // transitions f32 [32*32]
    const int*   tg = (const int*)d_in[2];     // tags i32 [512*2048]
    float* ws  = (float*)d_ws;
    float* out = (float*)d_out;

    hipLaunchKernelGGL(crf_nll_kernel, dim3(256), dim3(64), 0, stream, em, tr, tg, ws);
    hipLaunchKernelGGL(crf_reduce_kernel, dim3(1), dim3(64), 0, stream, ws, out);
}

// Round 2
// 169.035 us; speedup vs baseline: 2.3756x; 2.3756x over previous
//
#include <hip/hip_runtime.h>

#define L2E 1.4426950408889634f
#define LN2 0.6931471805599453f

typedef float f32x16 __attribute__((ext_vector_type(16)));
typedef short bf16x8 __attribute__((ext_vector_type(8)));
typedef unsigned int u32x4 __attribute__((ext_vector_type(4)));

__device__ __forceinline__ float dexp2(float x) { return __builtin_amdgcn_exp2f(x); }
__device__ __forceinline__ float dlog2(float x) { return __builtin_amdgcn_logf(x); }

__device__ __forceinline__ unsigned pkbf(float a, float b) {
    __bf16 ha = (__bf16)a, hb = (__bf16)b;
    unsigned short ua = __builtin_bit_cast(unsigned short, ha);
    unsigned short ub = __builtin_bit_cast(unsigned short, hb);
    return (unsigned)ua | ((unsigned)ub << 16);
}

// CRF forward via exp-domain transfer matrices.
// One WG (8 waves, 512 thr) per batch. Each wave builds 4 chunk matrices
// (64 steps each) with mfma_f32_32x32x16_bf16; phase 2 (wave 0) chains the
// 32 chunk matrices serially. Gold path score fused into emission staging.
__global__ __launch_bounds__(512, 4) void crf_phase_kernel(
    const float* __restrict__ em,   // [512][2048][32]
    const float* __restrict__ tr,   // [32][32] transitions[tag][prev]
    const int*   __restrict__ tgs,  // [512][2048]
    float*       __restrict__ ws)   // [512] per-batch nll
{
    __shared__ float s_tr[1024];                 // 4 KB
    __shared__ unsigned short s_mat[32 * 1024];  // 64 KB [chunk][col][row] bf16
    __shared__ float s_ring[8 * 256];            // 8 KB  [wave][8 slots][32]
    __shared__ float s_base[32];                 // per-chunk log2 scale
    __shared__ float s_gold[8];                  // per-wave gold partials

    const int tid = threadIdx.x;
    const int b   = blockIdx.x;
    const int w   = tid >> 6;
    const int l   = tid & 63;
    const int h   = l >> 5;
    const int q   = l & 31;   // A-row / B-D-column owned by this lane

    for (int k = tid; k < 1024; k += 512) s_tr[k] = tr[k];
    __syncthreads();

    // ---- constant A operand master (f32): ef[2j],ef[2j+1] for A dword j ----
    // A[i, k_hw] = E[i, pi(k_hw)], pi = swap bits 2<->3 (absorbs D->B repack).
    float ef[16];
#pragma unroll
    for (int j = 0; j < 8; ++j) {
        int k0  = 16 * (j >> 2) + 8 * h + 2 * (j & 3);
        int col = (k0 & ~12) | ((k0 & 4) << 1) | ((k0 & 8) >> 1);
        ef[2 * j]     = dexp2(s_tr[q * 32 + col] * L2E);
        ef[2 * j + 1] = dexp2(s_tr[q * 32 + col + 1] * L2E);
    }

    const float* ebase = em + ((size_t)b * 2048 + (size_t)w * 256) * 32;
    const int*   tgp   = tgs + (size_t)b * 2048;
    float*       ring  = s_ring + w * 256;

    unsigned bb[8];          // B fragments = current product R (bf16)
    float    s_cur = 1.f;    // pending 2^-k rescale (applied via A)
    int      k_cur = 0, sigma = 0;
    float    gold = 0.f;
    float4   r0, r1;
    int      tregC = 0, tlastC = 0, tregN = 0, tlastN = 0;

    auto eload = [&](int blk) -> float4 {
        int bb2 = blk > 31 ? 31 : blk;
        return *(const float4*)(ebase + ((bb2 * 8 + (l >> 3)) * 32 + (l & 7) * 4));
    };
    auto tagload = [&](int cl, int& treg, int& tlast) {
        int c0 = w * 256 + cl * 64;
        int idx = c0 - 1 + l; if (idx < 0) idx = 0;
        treg  = tgp[idx];
        tlast = tgp[c0 + 63];
    };

    r0 = eload(0); r1 = eload(1);
    tagload(0, tregC, tlastC);

#pragma unroll 1
    for (int blk = 0; blk < 32; ++blk) {
        if ((blk & 7) == 0) {
            int cl = blk >> 3;
            int cg = w * 4 + cl;
            if (cl > 0) { tregC = tregN; tlastC = tlastN; }
            // gold transition terms for this chunk (t = c0 .. c0+63)
            {
                int scur = __shfl(tregC, (l + 1) & 63, 64);
                int cur  = (l == 63) ? tlastC : scur;
                int prev = tregC;
                if (l == 0 && cg == 0) prev = 30;      // START
                gold += s_tr[cur * 32 + prev];
            }
            if (cl < 3) tagload(cl + 1, tregN, tlastN);
            // reset product R = I
            {
                int m = q >> 3, sel = q & 3;
                int d = 2 * m + (sel >> 1);
                bool match = ((q >> 2) & 1) == h;
                unsigned val = (sel & 1) ? 0x3F800000u : 0x00003F80u;
#pragma unroll
                for (int j = 0; j < 8; ++j) bb[j] = (match && j == d) ? val : 0u;
                s_cur = 1.f; k_cur = 0; sigma = 0;
            }
        }

        // ---- stage emissions for this block: gold pick + exp2 -> ring ----
        {
            int trel = (blk & 7) * 8 + (l >> 3);
            int tshf = __shfl(tregC, (trel + 1) & 63, 64);
            int tgt  = (trel == 63) ? tlastC : tshf;
            if ((tgt >> 2) == (l & 7)) {
                int sub = tgt & 3;
                float ev = sub == 0 ? r0.x : sub == 1 ? r0.y : sub == 2 ? r0.z : r0.w;
                gold += ev;
            }
            float4 dv;
            dv.x = dexp2(r0.x * L2E); dv.y = dexp2(r0.y * L2E);
            dv.z = dexp2(r0.z * L2E); dv.w = dexp2(r0.w * L2E);
            *(float4*)(ring + (l >> 3) * 32 + (l & 7) * 4) = dv;
        }
        r0 = r1; r1 = eload(blk + 2);

        // ---- 8 steps: R <- s * D_t * E * R ----
#pragma unroll
        for (int s = 0; s < 8; ++s) {
            sigma += k_cur;
            float dv  = ring[s * 32 + q];     // d[row=q], broadcast per half
            float dsc = dv * s_cur;
            unsigned a[8];
#pragma unroll
            for (int j = 0; j < 8; ++j)
                a[j] = pkbf(ef[2 * j] * dsc, ef[2 * j + 1] * dsc);
            bf16x8 A0 = __builtin_bit_cast(bf16x8, (u32x4){a[0], a[1], a[2], a[3]});
            bf16x8 A1 = __builtin_bit_cast(bf16x8, (u32x4){a[4], a[5], a[6], a[7]});
            bf16x8 B0 = __builtin_bit_cast(bf16x8, (u32x4){bb[0], bb[1], bb[2], bb[3]});
            bf16x8 B1 = __builtin_bit_cast(bf16x8, (u32x4){bb[4], bb[5], bb[6], bb[7]});
            f32x16 acc;
#pragma unroll
            for (int z = 0; z < 16; ++z) acc[z] = 0.f;
            acc = __builtin_amdgcn_mfma_f32_32x32x16_bf16(A0, B0, acc, 0, 0, 0);
            acc = __builtin_amdgcn_mfma_f32_32x32x16_bf16(A1, B1, acc, 0, 0, 0);
            // uniform power-of-2 rescale from R[0,0] (lane 0, acc[0])
            unsigned eb = (__float_as_uint(acc[0]) >> 23) & 0xFF;
            unsigned ku = (unsigned)__builtin_amdgcn_readfirstlane((int)eb);
            k_cur = (int)ku - 127;
            s_cur = __uint_as_float((254u - ku) << 23);
#pragma unroll
            for (int p = 0; p < 8; ++p) bb[p] = pkbf(acc[2 * p], acc[2 * p + 1]);
        }

        if ((blk & 7) == 7) {
            int cg = w * 4 + (blk >> 3);
#pragma unroll
            for (int j = 0; j < 8; ++j) {
                int k0   = 16 * (j >> 2) + 8 * h + 2 * (j & 3);
                int prow = (k0 & ~12) | ((k0 & 4) << 1) | ((k0 & 8) >> 1);
                *(unsigned*)(s_mat + cg * 1024 + q * 32 + prow) = bb[j];
            }
            if (l == 0) s_base[cg] = (float)sigma;
        }
    }

    // per-wave gold reduction
#pragma unroll
    for (int m = 1; m < 64; m <<= 1) gold += __shfl_xor(gold, m, 64);
    if (l == 0) s_gold[w] = gold;
    __syncthreads();

    // ---- phase 2: serial chain over 32 chunk matrices (lanes 0..31) ----
    if (tid < 32) {
        int i = tid;
        float x  = (i == 30) ? 1.f : 0.f;   // one-hot(START)
        float xb = 0.f, bs = 0.f;
        for (int c = 0; c < 32; ++c) {
            s_ring[i] = x;
            float yv[32];
#pragma unroll
            for (int j = 0; j < 8; ++j) *(float4*)&yv[4 * j] = *(const float4*)&s_ring[4 * j];
            float a2 = 0.f;
#pragma unroll
            for (int j = 0; j < 32; ++j) {
                unsigned short uv = s_mat[c * 1024 + j * 32 + i];
                a2 += __uint_as_float((unsigned)uv << 16) * yv[j];
            }
            unsigned eb2 = (__float_as_uint(a2) >> 23) & 0xFF;
            int ku0 = __shfl((int)eb2, 0, 32);
            x  = a2 * __uint_as_float((unsigned)(254 - ku0) << 23);
            xb += (float)(ku0 - 127);
            bs += s_base[c];
        }
        float dstop = dexp2(s_tr[31 * 32 + i] * L2E);
        float sv = x * dstop;
#pragma unroll
        for (int m2 = 1; m2 < 32; m2 <<= 1) sv += __shfl_xor(sv, m2, 32);
        float logZ = (xb + bs + dlog2(sv)) * LN2;
        if (i == 0) {
            float g = 0.f;
#pragma unroll
            for (int wv = 0; wv < 8; ++wv) g += s_gold[wv];
            g += s_tr[31 * 32 + tgp[2047]];   // STOP term
            ws[b] = logZ - g;
        }
    }
}

// Deterministic fixed-order reduction of the 512 per-batch values.
__global__ __launch_bounds__(64) void crf_reduce_kernel(
    const float* __restrict__ ws, float* __restrict__ out)
{
    int l = threadIdx.x;
    float s = 0.f;
#pragma unroll
    for (int k = 0; k < 8; ++k) s += ws[l + k * 64];
    s += __shfl_xor(s, 1, 64);
    s += __shfl_xor(s, 2, 64);
    s += __shfl_xor(s, 4, 64);
    s += __shfl_xor(s, 8, 64);
    s += __shfl_xor(s, 16, 64);
    s += __shfl_xor(s, 32, 64);
    if (l == 0) out[0] = s;
}

extern "C" void kernel_launch(void* const* d_in, const int* in_sizes, int n_in,
                              void* d_out, int out_size, void* d_ws, size_t ws_size,
                              hipStream_t stream)
{
    const float* em = (const float*)d_in[0];
    const float* tr = (const float*)d_in[1];
    const int*   tg = (const int*)d_in[2];
    float* ws  = (float*)d_ws;
    float* out = (float*)d_out;

    hipLaunchKernelGGL(crf_phase_kernel, dim3(512), dim3(512), 0, stream, em, tr, tg, ws);
    hipLaunchKernelGGL(crf_reduce_kernel, dim3(1), dim3(64), 0, stream, ws, out);
}

// Round 4
// 128.157 us; speedup vs baseline: 3.1333x; 1.3190x over previous
//
#include <hip/hip_runtime.h>

#define L2E 1.4426950408889634f
#define LN2 0.6931471805599453f

typedef float f32x16 __attribute__((ext_vector_type(16)));
typedef float f32x2  __attribute__((ext_vector_type(2)));
typedef short bf16x8 __attribute__((ext_vector_type(8)));
typedef unsigned int u32x4 __attribute__((ext_vector_type(4)));

__device__ __forceinline__ float dexp2(float x) { return __builtin_amdgcn_exp2f(x); }
__device__ __forceinline__ float dlog2(float x) { return __builtin_amdgcn_logf(x); }

// HW packed f32->2xbf16 convert (RNE). Inputs must be IR-produced VALU values
// (never raw MFMA accumulator regs) -- R3 post-mortem.
__device__ __forceinline__ unsigned cvtpk(float a, float b) {
    unsigned r;
    asm("v_cvt_pk_bf16_f32 %0, %1, %2" : "=v"(r) : "v"(a), "v"(b));
    return r;
}

// Software RNE pack (no asm): for cold paths that read raw MFMA results.
__device__ __forceinline__ unsigned pkrne(float a, float b) {
    unsigned ua = __float_as_uint(a), ub = __float_as_uint(b);
    ua += 0x7FFFu + ((ua >> 16) & 1u);
    ub += 0x7FFFu + ((ub >> 16) & 1u);
    return __builtin_amdgcn_perm(ub, ua, 0x07060302u);
}

// CRF forward via exp-domain transfer matrices (structure == R2, proven).
__global__ __launch_bounds__(512, 4) void crf_phase_kernel(
    const float* __restrict__ em,   // [512][2048][32]
    const float* __restrict__ tr,   // [32][32] transitions[tag][prev]
    const int*   __restrict__ tgs,  // [512][2048]
    float*       __restrict__ ws)   // [512] per-batch nll
{
    __shared__ float s_tr[1024];                 // 4 KB
    __shared__ unsigned short s_mat[32 * 1024];  // 64 KB [chunk][col][row] bf16
    __shared__ float s_ring[8 * 256];            // 8 KB  [wave][8 slots][32]
    __shared__ float s_base[32];
    __shared__ float s_gold[8];

    const int tid = threadIdx.x;
    const int b   = blockIdx.x;
    const int w   = tid >> 6;
    const int l   = tid & 63;
    const int h   = l >> 5;
    const int q   = l & 31;

    for (int k = tid; k < 1024; k += 512) s_tr[k] = tr[k];
    __syncthreads();

    // Constant A master (f32): A[i,k_hw] = E[i,pi(k_hw)], pi = swap bits 2<->3.
    f32x2 efv[8];
#pragma unroll
    for (int j = 0; j < 8; ++j) {
        int k0  = 16 * (j >> 2) + 8 * h + 2 * (j & 3);
        int col = (k0 & ~12) | ((k0 & 4) << 1) | ((k0 & 8) >> 1);
        efv[j].x = dexp2(s_tr[q * 32 + col] * L2E);
        efv[j].y = dexp2(s_tr[q * 32 + col + 1] * L2E);
    }

    f32x16 zro;
#pragma unroll
    for (int z = 0; z < 16; ++z) zro[z] = 0.f;

    const float* ebase = em + ((size_t)b * 2048 + (size_t)w * 256) * 32;
    const int*   tgp   = tgs + (size_t)b * 2048;
    float*       ring  = s_ring + w * 256;

    f32x16 acc;              // carried product state (f32)
    float  s_cur = 1.f;      // 2^-k_cur pending rescale (applied to B)
    int    k_cur = 0, sigma = 0;
    float  gold = 0.f;
    float4 r0, r1;
    int    tregC = 0, tlastC = 0, tregN = 0, tlastN = 0;

    auto eload = [&](int blk) -> float4 {
        int bb2 = blk > 31 ? 31 : blk;
        return *(const float4*)(ebase + ((bb2 * 8 + (l >> 3)) * 32 + (l & 7) * 4));
    };
    auto tagload = [&](int cl, int& treg, int& tlast) {
        int c0 = w * 256 + cl * 64;
        int idx = c0 - 1 + l; if (idx < 0) idx = 0;
        treg  = tgp[idx];
        tlast = tgp[c0 + 63];
    };

    r0 = eload(0); r1 = eload(1);
    tagload(0, tregC, tlastC);

#pragma unroll 1
    for (int blk = 0; blk < 32; ++blk) {
        if ((blk & 7) == 0) {
            int cl = blk >> 3;
            int cg = w * 4 + cl;
            if (cl > 0) { tregC = tregN; tlastC = tlastN; }
            {   // gold transition terms for this chunk
                int scur = __shfl(tregC, (l + 1) & 63, 64);
                int cur  = (l == 63) ? tlastC : scur;
                int prev = tregC;
                if (l == 0 && cg == 0) prev = 30;      // START
                gold += s_tr[cur * 32 + prev];
            }
            if (cl < 3) tagload(cl + 1, tregN, tlastN);
            // reset product to identity (f32, C/D layout)
#pragma unroll
            for (int r = 0; r < 16; ++r)
                acc[r] = ((((r & 3) + 8 * (r >> 2) + 4 * h) == q) ? 1.f : 0.f);
            s_cur = 1.f; k_cur = 0; sigma = 0;
        }

        // ---- stage emissions: gold pick + exp2 -> ring ----
        {
            int trel = (blk & 7) * 8 + (l >> 3);
            int tshf = __shfl(tregC, (trel + 1) & 63, 64);
            int tgt  = (trel == 63) ? tlastC : tshf;
            if ((tgt >> 2) == (l & 7)) {
                int sub = tgt & 3;
                float ev = sub == 0 ? r0.x : sub == 1 ? r0.y : sub == 2 ? r0.z : r0.w;
                gold += ev;
            }
            float4 dv;
            dv.x = dexp2(r0.x * L2E); dv.y = dexp2(r0.y * L2E);
            dv.z = dexp2(r0.z * L2E); dv.w = dexp2(r0.w * L2E);
            *(float4*)(ring + (l >> 3) * 32 + (l & 7) * 4) = dv;
        }
        r0 = r1; r1 = eload(blk + 2);

        // ---- 8 steps: acc <- (dv*E) * (s_cur*acc) ----
#pragma unroll
        for (int s = 0; s < 8; ++s) {
            sigma += k_cur;
            float dv = ring[s * 32 + q];      // d[row=q], broadcast per half
            f32x2 dv2; dv2.x = dv;    dv2.y = dv;
            f32x2 sc2; sc2.x = s_cur; sc2.y = s_cur;
            unsigned aa[8], bbn[8];
#pragma unroll
            for (int j = 0; j < 8; ++j) {
                f32x2 m = efv[j] * dv2;                 // v_pk_mul_f32
                aa[j] = cvtpk(m.x, m.y);
                f32x2 p; p.x = acc[2 * j]; p.y = acc[2 * j + 1];
                p = p * sc2;                            // v_pk_mul_f32
                bbn[j] = cvtpk(p.x, p.y);
            }
            bf16x8 A0 = __builtin_bit_cast(bf16x8, (u32x4){aa[0], aa[1], aa[2], aa[3]});
            bf16x8 A1 = __builtin_bit_cast(bf16x8, (u32x4){aa[4], aa[5], aa[6], aa[7]});
            bf16x8 B0 = __builtin_bit_cast(bf16x8, (u32x4){bbn[0], bbn[1], bbn[2], bbn[3]});
            bf16x8 B1 = __builtin_bit_cast(bf16x8, (u32x4){bbn[4], bbn[5], bbn[6], bbn[7]});
            f32x16 t = __builtin_amdgcn_mfma_f32_32x32x16_bf16(A0, B0, zro, 0, 0, 0);
            acc = __builtin_amdgcn_mfma_f32_32x32x16_bf16(A1, B1, t, 0, 0, 0);
            // uniform power-of-2 rescale from R[0,0]
            unsigned eb = (__float_as_uint(acc[0]) >> 23) & 0xFF;
            unsigned ku = (unsigned)__builtin_amdgcn_readfirstlane((int)eb);
            k_cur = (int)ku - 127;
            s_cur = __uint_as_float((254u - ku) << 23);
        }

        if ((blk & 7) == 7) {
            int cg = w * 4 + (blk >> 3);
#pragma unroll
            for (int p = 0; p < 8; ++p) {
                int rrow = ((2 * p) & 3) + 8 * ((2 * p) >> 2) + 4 * h;
                *(unsigned*)(s_mat + cg * 1024 + q * 32 + rrow) =
                    pkrne(acc[2 * p], acc[2 * p + 1]);   // raw acc -> software pack
            }
            if (l == 0) s_base[cg] = (float)sigma;
        }
    }

    // per-wave gold reduction
#pragma unroll
    for (int m = 1; m < 64; m <<= 1) gold += __shfl_xor(gold, m, 64);
    if (l == 0) s_gold[w] = gold;
    __syncthreads();

    // ---- phase 2: serial chain over 32 chunk matrices (lanes 0..31) ----
    if (tid < 32) {
        int i = tid;
        float x  = (i == 30) ? 1.f : 0.f;   // one-hot(START)
        float xb = 0.f, bs = 0.f;
        for (int c = 0; c < 32; ++c) {
            s_ring[i] = x;
            float yv[32];
#pragma unroll
            for (int j = 0; j < 8; ++j) *(float4*)&yv[4 * j] = *(const float4*)&s_ring[4 * j];
            float a2 = 0.f;
#pragma unroll
            for (int j = 0; j < 32; ++j) {
                unsigned short uv = s_mat[c * 1024 + j * 32 + i];
                a2 += __uint_as_float((unsigned)uv << 16) * yv[j];
            }
            unsigned eb2 = (__float_as_uint(a2) >> 23) & 0xFF;
            int ku0 = __shfl((int)eb2, 0, 32);
            x  = a2 * __uint_as_float((unsigned)(254 - ku0) << 23);
            xb += (float)(ku0 - 127);
            bs += s_base[c];
        }
        float dstop = dexp2(s_tr[31 * 32 + i] * L2E);
        float sv = x * dstop;
#pragma unroll
        for (int m2 = 1; m2 < 32; m2 <<= 1) sv += __shfl_xor(sv, m2, 32);
        float logZ = (xb + bs + dlog2(sv)) * LN2;
        if (i == 0) {
            float g = 0.f;
#pragma unroll
            for (int wv = 0; wv < 8; ++wv) g += s_gold[wv];
            g += s_tr[31 * 32 + tgp[2047]];   // STOP term
            ws[b] = logZ - g;
        }
    }
}

// Deterministic fixed-order reduction of the 512 per-batch values.
__global__ __launch_bounds__(64) void crf_reduce_kernel(
    const float* __restrict__ ws, float* __restrict__ out)
{
    int l = threadIdx.x;
    float s = 0.f;
#pragma unroll
    for (int k = 0; k < 8; ++k) s += ws[l + k * 64];
    s += __shfl_xor(s, 1, 64);
    s += __shfl_xor(s, 2, 64);
    s += __shfl_xor(s, 4, 64);
    s += __shfl_xor(s, 8, 64);
    s += __shfl_xor(s, 16, 64);
    s += __shfl_xor(s, 32, 64);
    if (l == 0) out[0] = s;
}

extern "C" void kernel_launch(void* const* d_in, const int* in_sizes, int n_in,
                              void* d_out, int out_size, void* d_ws, size_t ws_size,
                              hipStream_t stream)
{
    const float* em = (const float*)d_in[0];
    const float* tr = (const float*)d_in[1];
    const int*   tg = (const int*)d_in[2];
    float* ws  = (float*)d_ws;
    float* out = (float*)d_out;

    hipLaunchKernelGGL(crf_phase_kernel, dim3(512), dim3(512), 0, stream, em, tr, tg, ws);
    hipLaunchKernelGGL(crf_reduce_kernel, dim3(1), dim3(64), 0, stream, ws, out);
}

// Round 5
// 112.297 us; speedup vs baseline: 3.5758x; 1.1412x over previous
//
#include <hip/hip_runtime.h>

#define L2E 1.4426950408889634f
#define LN2 0.6931471805599453f

typedef float f32x16 __attribute__((ext_vector_type(16)));
typedef float f32x2  __attribute__((ext_vector_type(2)));
typedef short bf16x8 __attribute__((ext_vector_type(8)));
typedef unsigned int u32x4 __attribute__((ext_vector_type(4)));

__device__ __forceinline__ float dexp2(float x) { return __builtin_amdgcn_exp2f(x); }
__device__ __forceinline__ float dlog2(float x) { return __builtin_amdgcn_logf(x); }

// HW packed f32->2xbf16 (RNE). Inputs must be IR-produced VALU values
// (never raw MFMA accumulator regs) -- R3 post-mortem.
__device__ __forceinline__ unsigned cvtpk(float a, float b) {
    unsigned r;
    asm("v_cvt_pk_bf16_f32 %0, %1, %2" : "=v"(r) : "v"(a), "v"(b));
    return r;
}

// Software RNE pack (pure IR): for cold paths reading raw MFMA results.
__device__ __forceinline__ unsigned pkrne(float a, float b) {
    unsigned ua = __float_as_uint(a), ub = __float_as_uint(b);
    ua += 0x7FFFu + ((ua >> 16) & 1u);
    ub += 0x7FFFu + ((ub >> 16) & 1u);
    return __builtin_amdgcn_perm(ub, ua, 0x07060302u);
}

// CRF forward via exp-domain transfer matrices, C-form chain:
//   tau_t = E * (D_t * tau_{t-1}),  tau_0 = E[:,START]
// A-operand = E is CONSTANT (packed bf16 once); D_t is a B-side row scale
// fused into the per-step acc->bf16 pack. 2047 steps total; the final
// step's D_2048 is applied in the phase-2 epilogue dot product.
__global__ __launch_bounds__(512, 4) void crf_phase_kernel(
    const float* __restrict__ em,   // [512][2048][32]
    const float* __restrict__ tr,   // [32][32] transitions[tag][prev]
    const int*   __restrict__ tgs,  // [512][2048]
    float*       __restrict__ ws)   // [512] per-batch nll
{
    __shared__ float s_tr[1024];                 // 4 KB
    __shared__ unsigned short s_mat[32 * 1024];  // 64 KB [chunk][col][row] bf16
    __shared__ float s_ring[8 * 256];            // 8 KB  [wave][8 slots][32]
    __shared__ float s_base[32];
    __shared__ float s_gold[8];

    const int tid = threadIdx.x;
    const int b   = blockIdx.x;
    const int w   = tid >> 6;
    const int l   = tid & 63;
    const int h   = l >> 5;
    const int q   = l & 31;

    for (int k = tid; k < 1024; k += 512) s_tr[k] = tr[k];
    __syncthreads();

    // Constant A = E with pi'd columns (pi = swap bits 2<->3), bf16, packed once.
    unsigned ea[8];
#pragma unroll
    for (int j = 0; j < 8; ++j) {
        int k0  = 16 * (j >> 2) + 8 * h + 2 * (j & 3);
        int col = (k0 & ~12) | ((k0 & 4) << 1) | ((k0 & 8) >> 1);
        ea[j] = pkrne(dexp2(s_tr[q * 32 + col] * L2E),
                      dexp2(s_tr[q * 32 + col + 1] * L2E));
    }
    const bf16x8 A0 = __builtin_bit_cast(bf16x8, (u32x4){ea[0], ea[1], ea[2], ea[3]});
    const bf16x8 A1 = __builtin_bit_cast(bf16x8, (u32x4){ea[4], ea[5], ea[6], ea[7]});

    f32x16 zro;
#pragma unroll
    for (int z = 0; z < 16; ++z) zro[z] = 0.f;

    const float* ebase = em + ((size_t)b * 2048 + (size_t)w * 256) * 32;
    const int*   tgp   = tgs + (size_t)b * 2048;
    float*       ring  = s_ring + w * 256;

    f32x16 acc;              // carried chunk product (f32, C/D layout)
    float  s_cur = 1.f;      // pending 2^-k rescale (applied at s==0/s==4 packs)
    int    k_pend = 0, sigma = 0;
    float  gold = 0.f;
    float4 r0, r1;
    int    tregC = 0, tlastC = 0, tregN = 0, tlastN = 0;

    auto eload = [&](int blk) -> float4 {
        int bb2 = blk > 31 ? 31 : blk;
        return *(const float4*)(ebase + ((bb2 * 8 + (l >> 3)) * 32 + (l & 7) * 4));
    };
    auto tagload = [&](int cl, int& treg, int& tlast) {
        int c0 = w * 256 + cl * 64;
        int idx = c0 - 1 + l; if (idx < 0) idx = 0;
        treg  = tgp[idx];
        tlast = tgp[c0 + 63];
    };

    r0 = eload(0); r1 = eload(1);
    tagload(0, tregC, tlastC);

#pragma unroll 1
    for (int blk = 0; blk < 32; ++blk) {
        if ((blk & 7) == 0) {
            int cl = blk >> 3;
            int cg = w * 4 + cl;
            if (cl > 0) { tregC = tregN; tlastC = tlastN; }
            {   // gold transition terms for this chunk
                int scur = __shfl(tregC, (l + 1) & 63, 64);
                int cur  = (l == 63) ? tlastC : scur;
                int prev = tregC;
                if (l == 0 && cg == 0) prev = 30;      // START
                gold += s_tr[cur * 32 + prev];
            }
            if (cl < 3) tagload(cl + 1, tregN, tlastN);
            // reset product to identity (f32, C/D layout)
#pragma unroll
            for (int r = 0; r < 16; ++r)
                acc[r] = ((((r & 3) + 8 * (r >> 2) + 4 * h) == q) ? 1.f : 0.f);
            s_cur = 1.f; k_pend = 0; sigma = 0;
        }

        // ---- stage d_t = exp(e_t): gold pick + exp2 -> ring (natural order) ----
        {
            int trel = (blk & 7) * 8 + (l >> 3);
            int tshf = __shfl(tregC, (trel + 1) & 63, 64);
            int tgt  = (trel == 63) ? tlastC : tshf;
            if ((tgt >> 2) == (l & 7)) {
                int sub = tgt & 3;
                float ev = sub == 0 ? r0.x : sub == 1 ? r0.y : sub == 2 ? r0.z : r0.w;
                gold += ev;
            }
            float4 dv;
            dv.x = dexp2(r0.x * L2E); dv.y = dexp2(r0.y * L2E);
            dv.z = dexp2(r0.z * L2E); dv.w = dexp2(r0.w * L2E);
            *(float4*)(ring + (l >> 3) * 32 + (l & 7) * 4) = dv;
        }
        r0 = r1; r1 = eload(blk + 2);

        const bool skiplast = (blk == 31) && (w == 7);  // global step 2048

        // ---- 8 steps: acc <- E * (d_t o (s*acc)) ; A constant ----
#pragma unroll
        for (int s = 0; s < 8; ++s) {
            if (s == 7 && skiplast) continue;
            const float4* rp = (const float4*)(ring + s * 32 + h * 4);
            unsigned bbn[8];
#pragma unroll
            for (int q2 = 0; q2 < 4; ++q2) {
                float4 d4 = rp[q2 * 2];   // d[8q2+4h .. +3], broadcast per half
                f32x2 a0; a0.x = acc[4 * q2 + 0]; a0.y = acc[4 * q2 + 1];
                f32x2 d0; d0.x = d4.x; d0.y = d4.y;
                f32x2 m0 = a0 * d0;
                f32x2 a1; a1.x = acc[4 * q2 + 2]; a1.y = acc[4 * q2 + 3];
                f32x2 d1; d1.x = d4.z; d1.y = d4.w;
                f32x2 m1 = a1 * d1;
                if (s == 0 || s == 4) {
                    f32x2 sc; sc.x = s_cur; sc.y = s_cur;
                    m0 = m0 * sc; m1 = m1 * sc;
                }
                bbn[2 * q2]     = cvtpk(m0.x, m0.y);
                bbn[2 * q2 + 1] = cvtpk(m1.x, m1.y);
            }
            if (s == 0 || s == 4) sigma += k_pend;
            bf16x8 B0 = __builtin_bit_cast(bf16x8, (u32x4){bbn[0], bbn[1], bbn[2], bbn[3]});
            bf16x8 B1 = __builtin_bit_cast(bf16x8, (u32x4){bbn[4], bbn[5], bbn[6], bbn[7]});
            f32x16 t = __builtin_amdgcn_mfma_f32_32x32x16_bf16(A0, B0, zro, 0, 0, 0);
            acc = __builtin_amdgcn_mfma_f32_32x32x16_bf16(A1, B1, t, 0, 0, 0);
            if (s == 3 || s == 7) {
                unsigned eb = (__float_as_uint(acc[0]) >> 23) & 0xFF;
                unsigned ku = (unsigned)__builtin_amdgcn_readfirstlane((int)eb);
                k_pend = (int)ku - 127;
                s_cur = __uint_as_float((254u - ku) << 23);
            }
        }

        if ((blk & 7) == 7) {
            int cg = w * 4 + (blk >> 3);
#pragma unroll
            for (int p = 0; p < 8; ++p) {
                int rrow = ((2 * p) & 3) + 8 * ((2 * p) >> 2) + 4 * h;
                *(unsigned*)(s_mat + cg * 1024 + q * 32 + rrow) =
                    pkrne(acc[2 * p], acc[2 * p + 1]);
            }
            if (l == 0) s_base[cg] = (float)sigma;
        }
    }

    // per-wave gold reduction
#pragma unroll
    for (int m = 1; m < 64; m <<= 1) gold += __shfl_xor(gold, m, 64);
    if (l == 0) s_gold[w] = gold;
    __syncthreads();

    // ---- phase 2: serial chain over 32 chunk matrices (lanes 0..31) ----
    if (tid < 32) {
        int i = tid;
        float x  = dexp2(s_tr[i * 32 + 30] * L2E);   // tau_0 = E[:,START]
        float xb = 0.f, bs = 0.f;
        for (int c = 0; c < 32; ++c) {
            s_ring[i] = x;
            float yv[32];
#pragma unroll
            for (int j = 0; j < 8; ++j) *(float4*)&yv[4 * j] = *(const float4*)&s_ring[4 * j];
            float a2 = 0.f;
#pragma unroll
            for (int j = 0; j < 32; ++j) {
                unsigned short uv = s_mat[c * 1024 + j * 32 + i];
                a2 += __uint_as_float((unsigned)uv << 16) * yv[j];
            }
            unsigned eb2 = (__float_as_uint(a2) >> 23) & 0xFF;
            int ku0 = __shfl((int)eb2, 0, 32);
            x  = a2 * __uint_as_float((unsigned)(254 - ku0) << 23);
            xb += (float)(ku0 - 127);
            bs += s_base[c];
        }
        // final: Z = sum_i exp(tr[STOP,i] + e_2048[i]) * tau_2047[i]
        float elast = em[((size_t)b * 2048 + 2047) * 32 + i];
        float wv = dexp2((s_tr[31 * 32 + i] + elast) * L2E);
        float sv = x * wv;
#pragma unroll
        for (int m2 = 1; m2 < 32; m2 <<= 1) sv += __shfl_xor(sv, m2, 32);
        float logZ = (xb + bs + dlog2(sv)) * LN2;
        if (i == 0) {
            float g = 0.f;
#pragma unroll
            for (int wv2 = 0; wv2 < 8; ++wv2) g += s_gold[wv2];
            g += s_tr[31 * 32 + tgp[2047]];   // STOP term
            ws[b] = logZ - g;
        }
    }
}

// Deterministic fixed-order reduction of the 512 per-batch values.
__global__ __launch_bounds__(64) void crf_reduce_kernel(
    const float* __restrict__ ws, float* __restrict__ out)
{
    int l = threadIdx.x;
    float s = 0.f;
#pragma unroll
    for (int k = 0; k < 8; ++k) s += ws[l + k * 64];
    s += __shfl_xor(s, 1, 64);
    s += __shfl_xor(s, 2, 64);
    s += __shfl_xor(s, 4, 64);
    s += __shfl_xor(s, 8, 64);
    s += __shfl_xor(s, 16, 64);
    s += __shfl_xor(s, 32, 64);
    if (l == 0) out[0] = s;
}

extern "C" void kernel_launch(void* const* d_in, const int* in_sizes, int n_in,
                              void* d_out, int out_size, void* d_ws, size_t ws_size,
                              hipStream_t stream)
{
    const float* em = (const float*)d_in[0];
    const float* tr = (const float*)d_in[1];
    const int*   tg = (const int*)d_in[2];
    float* ws  = (float*)d_ws;
    float* out = (float*)d_out;

    hipLaunchKernelGGL(crf_phase_kernel, dim3(512), dim3(512), 0, stream, em, tr, tg, ws);
    hipLaunchKernelGGL(crf_reduce_kernel, dim3(1), dim3(64), 0, stream, ws, out);
}